// Round 2
// baseline (2389.928 us; speedup 1.0000x reference)
//
#include <hip/hip_runtime.h>
#include <stdint.h>

// Problem constants (fixed by the reference)
#define Bn 32
#define Cn 64
#define Vn 1024
#define Tn 24
#define Gn 192   // 3*C
#define O4 256   // 4*C

typedef __attribute__((ext_vector_type(8))) short bh8;   // 8 x bf16 (MFMA A/B frag)
typedef __attribute__((ext_vector_type(4))) short bh4;   // 4 x bf16 packed store
typedef __attribute__((ext_vector_type(4))) float f32x4; // MFMA C/D frag

__device__ __forceinline__ float bf2f(unsigned short u){
  union { unsigned int i; float f; } x; x.i = ((unsigned int)u) << 16; return x.f;
}
__device__ __forceinline__ unsigned short f2bf(float f){
  union { float f; unsigned int i; } x; x.f = f;
  unsigned int u = x.i;
  return (unsigned short)((u + 0x7fffu + ((u >> 16) & 1u)) >> 16); // RNE
}
__device__ __forceinline__ float sigm(float x){
  return __builtin_amdgcn_rcpf(1.f + __expf(-x));
}
__device__ __forceinline__ float tanhfast(float x){
  return 1.f - 2.f * __builtin_amdgcn_rcpf(__expf(2.f*x) + 1.f);
}
__device__ __forceinline__ f32x4 fzero(){ f32x4 z = {0.f,0.f,0.f,0.f}; return z; }

// MFMA 16x16x32 frag loader (TN convention: both operands row-major with k contiguous).
// lane l holds X[idx = r0 + mf*16 + (l&15)][k = k0 + (l>>4)*8 + j], j=0..7  -> one b128 load.
__device__ __forceinline__ bh8 ld_frag(const unsigned short* base, int stride, int r0, int mf,
                                       int k0, int lane){
  int r  = r0 + mf*16 + (lane & 15);
  int kk = k0 + ((lane >> 4) << 3);
  return *(const bh8*)(base + (size_t)r * stride + kk);
}

// ---------------------------------------------------------------------------
// Prep: permute W_gout rows to o' = c*4 + gate (one lane's f32x4 acc = i,f,g,o of one
// channel), quantize to bf16; permute bias; quantize W_out.
__global__ void k_prep_w(const float* __restrict__ Wg, const float* __restrict__ bg,
                         const float* __restrict__ Wo,
                         unsigned short* __restrict__ Wperm, float* __restrict__ bperm,
                         unsigned short* __restrict__ Woutb){
  int op = threadIdx.x;              // 0..255 = o'
  int gate = op & 3, c = op >> 2;
  int oo = gate * 64 + c;            // original row in W_gout
  for (int g = 0; g < Gn; ++g)
    Wperm[op * Gn + g] = f2bf(Wg[(size_t)oo * Gn + g]);
  bperm[op] = bg[oo];
  if (op < 64)
    for (int cc = 0; cc < 64; ++cc)
      Woutb[op * 64 + cc] = f2bf(Wo[(size_t)op * 64 + cc]);
}

// Quantize + transpose a 1024x1024 fp32 matrix: dst (optional) = bf16(src), dstT = bf16(src^T)
__global__ void k_transq(const float* __restrict__ src, unsigned short* dst,
                         unsigned short* __restrict__ dstT){
  __shared__ float tile[64][65];
  int j0 = blockIdx.x * 64, i0 = blockIdx.y * 64;
  for (int e = threadIdx.x; e < 4096; e += 256){
    int r = e >> 6, col = e & 63;
    float v = src[(size_t)(i0 + r) * Vn + j0 + col];
    if (dst) dst[(size_t)(i0 + r) * Vn + j0 + col] = f2bf(v);
    tile[r][col] = v;
  }
  __syncthreads();
  for (int e = threadIdx.x; e < 4096; e += 256){
    int r = e >> 6, col = e & 63;
    dstT[(size_t)(j0 + r) * Vn + i0 + col] = f2bf(tile[col][r]);
  }
}

// A2 = A @ A  (bf16 MFMA, fp32 out). D[m][n] = sum_k Ab[m][k] * ATb[n][k].
__global__ __launch_bounds__(64) void k_gemm_a2(const unsigned short* __restrict__ Ab,
                                                const unsigned short* __restrict__ ATb,
                                                float* __restrict__ A2){
  int lane = threadIdx.x;
  int n0 = blockIdx.x * 64, m0 = blockIdx.y * 64;
  f32x4 acc[4][4];
  #pragma unroll
  for (int i=0;i<4;i++)
    #pragma unroll
    for (int j=0;j<4;j++) acc[i][j] = fzero();
  #pragma unroll 2
  for (int k = 0; k < Vn; k += 32){
    bh8 a[4], b[4];
    #pragma unroll
    for (int mf=0; mf<4; ++mf) a[mf] = ld_frag(Ab, Vn, m0, mf, k, lane);
    #pragma unroll
    for (int nf=0; nf<4; ++nf) b[nf] = ld_frag(ATb, Vn, n0, nf, k, lane);
    #pragma unroll
    for (int mf=0; mf<4; ++mf)
      #pragma unroll
      for (int nf=0; nf<4; ++nf)
        acc[mf][nf] = __builtin_amdgcn_mfma_f32_16x16x32_bf16(a[mf], b[nf], acc[mf][nf], 0,0,0);
  }
  #pragma unroll
  for (int mf=0; mf<4; ++mf){
    int rb = m0 + mf*16 + ((lane>>4)<<2);
    #pragma unroll
    for (int nf=0; nf<4; ++nf){
      int cc = n0 + nf*16 + (lane&15);
      #pragma unroll
      for (int r=0;r<4;r++) A2[(size_t)(rb+r)*Vn + cc] = acc[mf][nf][r];
    }
  }
}

// x (B,C,V,T) fp32 -> xTc[t][b][v][c] bf16 (c contiguous). Fully coalesced via LDS tile.
// Block: (v-chunk of 16, b). Reads 64c x 16v x 24t contiguous runs; writes full 64B lines.
__global__ __launch_bounds__(256) void k_transpose_x(const float* __restrict__ x,
                                                     unsigned short* __restrict__ xT){
  __shared__ unsigned short tile[16][24][66];  // [v][t][c] bf16, padded
  int b = blockIdx.y, v0 = blockIdx.x * 16;
  int tid = threadIdx.x;
  for (int e = tid; e < 6144; e += 256){       // 64c*16v rows x 6 float4
    int row = e / 6, q = e - row*6;
    int c = row >> 4, vl = row & 15;
    const float4 f = *(const float4*)(x + (((size_t)(b*64 + c))*Vn + v0 + vl)*(size_t)Tn + q*4);
    tile[vl][q*4+0][c] = f2bf(f.x);
    tile[vl][q*4+1][c] = f2bf(f.y);
    tile[vl][q*4+2][c] = f2bf(f.z);
    tile[vl][q*4+3][c] = f2bf(f.w);
  }
  __syncthreads();
  for (int e = tid; e < 12288; e += 256){      // 24t x 16v x 32 cpair
    int cp = e & 31, vl = (e >> 5) & 15, tt = e >> 9;
    unsigned int val = (unsigned int)tile[vl][tt][cp*2] |
                       ((unsigned int)tile[vl][tt][cp*2+1] << 16);
    *(unsigned int*)(xT + ((size_t)(tt*Bn + b))*Vn*Cn + (size_t)(v0+vl)*Cn + cp*2) = val;
  }
}

// comb = x_t + h (used only for t=0). Writes combc[b][v][c] and combmk[b*C+c][v].
__global__ __launch_bounds__(256) void k_comb(const unsigned short* __restrict__ xTc,
    const unsigned short* __restrict__ ys,
    unsigned short* __restrict__ combc, unsigned short* __restrict__ combmk, int t){
  __shared__ float tile[64][65];
  int b = blockIdx.y, v0 = blockIdx.x * 64;
  const unsigned short* xp = xTc + ((size_t)t*Bn + b) * Vn * Cn;
  const unsigned short* hp = ys  + ((size_t)t*Bn + b) * Vn * Cn;
  for (int e = threadIdx.x; e < 4096; e += 256){
    int vl = e >> 6, c = e & 63;
    size_t o = (size_t)(v0 + vl) * Cn + c;
    float s = bf2f(xp[o]) + bf2f(hp[o]);
    combc[(size_t)b*Vn*Cn + o] = f2bf(s);
    tile[vl][c] = s;
  }
  __syncthreads();
  for (int e = threadIdx.x; e < 4096; e += 256){
    int c = e >> 6, vl = e & 63;
    combmk[((size_t)b*Cn + c)*Vn + v0 + vl] = f2bf(tile[vl][c]);
  }
}

// ---------------------------------------------------------------------------
// Fused per-step kernel: dual GEMM (x1=comb@A, x2=comb@A2) -> LDS -> gates GEMM ->
// LSTM pointwise -> writes h (ys plane t+1) and next-step comb (both layouts).
// Grid (16 v-tiles, 32 b), 64 threads (one wave).
__global__ __launch_bounds__(64) void k_step(
    const unsigned short* __restrict__ comb_mk,   // current comb, [b*C+c][v]
    const unsigned short* __restrict__ combc,     // current comb, [b][v][c]
    const unsigned short* __restrict__ ATb,       // A^T bf16 [w][v]
    const unsigned short* __restrict__ A2Tb,      // (A^2)^T bf16 [w][v]
    const unsigned short* __restrict__ Wperm,     // [256][192]
    const float* __restrict__ bperm,              // [256]
    const unsigned short* __restrict__ xTc,       // [t][b][v][c]
    float* __restrict__ cst,                      // [b][c][v] fp32 cell state
    unsigned short* __restrict__ ys,              // [t+1][b][v][c] h planes
    unsigned short* __restrict__ comb_mk_nxt,     // next comb, [b*C+c][v]
    unsigned short* __restrict__ combc_nxt,       // next comb, [b][v][c]
    int t){
  __shared__ unsigned short x1t[64][72];
  __shared__ unsigned short x2t[64][72];
  __shared__ unsigned short hyt[64][72];
  __shared__ unsigned short cmt[64][72];
  int lane = threadIdx.x;
  int n0 = blockIdx.x * 64;       // v-tile (w)
  int b  = blockIdx.y;
  int m0 = b * 64;

  // ---- Phase A: dual GEMM over K=V
  f32x4 acc1[4][4], acc2[4][4];
  #pragma unroll
  for (int i=0;i<4;i++)
    #pragma unroll
    for (int j=0;j<4;j++){ acc1[i][j] = fzero(); acc2[i][j] = fzero(); }
  #pragma unroll 2
  for (int k = 0; k < Vn; k += 32){
    bh8 a[4], b1[4], b2[4];
    #pragma unroll
    for (int mf=0; mf<4; ++mf) a[mf]  = ld_frag(comb_mk, Vn, m0, mf, k, lane);
    #pragma unroll
    for (int nf=0; nf<4; ++nf) b1[nf] = ld_frag(ATb,  Vn, n0, nf, k, lane);
    #pragma unroll
    for (int nf=0; nf<4; ++nf) b2[nf] = ld_frag(A2Tb, Vn, n0, nf, k, lane);
    #pragma unroll
    for (int mf=0; mf<4; ++mf)
      #pragma unroll
      for (int nf=0; nf<4; ++nf){
        acc1[mf][nf] = __builtin_amdgcn_mfma_f32_16x16x32_bf16(a[mf], b1[nf], acc1[mf][nf], 0,0,0);
        acc2[mf][nf] = __builtin_amdgcn_mfma_f32_16x16x32_bf16(a[mf], b2[nf], acc2[mf][nf], 0,0,0);
      }
  }

  // ---- Phase B: stash x1,x2 tiles to LDS in [v][c] layout
  #pragma unroll
  for (int mf=0; mf<4; ++mf){
    int cb = mf*16 + ((lane>>4)<<2);
    #pragma unroll
    for (int nf=0; nf<4; ++nf){
      int vl = nf*16 + (lane&15);
      bh4 p1, p2;
      #pragma unroll
      for (int r=0;r<4;r++){ p1[r] = (short)f2bf(acc1[mf][nf][r]); p2[r] = (short)f2bf(acc2[mf][nf][r]); }
      *(bh4*)&x1t[vl][cb] = p1;
      *(bh4*)&x2t[vl][cb] = p2;
    }
  }
  __syncthreads();

  // ---- Phase C: gates GEMM (all 256 o' rows, in 4 chunks) + fused LSTM pointwise
  const unsigned short* cbase = combc + (size_t)b * Vn * Cn;
  const unsigned short* xnp = xTc + ((size_t)(t+1)*Bn + b) * Vn * Cn;   // only read if t<23
  #pragma unroll
  for (int mc = 0; mc < 4; ++mc){
    f32x4 g[4][4];
    #pragma unroll
    for (int i=0;i<4;i++)
      #pragma unroll
      for (int j=0;j<4;j++) g[i][j] = fzero();
    #pragma unroll
    for (int ki = 0; ki < 6; ++ki){
      int hop = ki >> 1, koff = (ki & 1) * 32;
      bh8 a[4], bb[4];
      #pragma unroll
      for (int mf=0; mf<4; ++mf) a[mf] = ld_frag(Wperm, Gn, mc*64, mf, hop*64 + koff, lane);
      if (hop == 0){
        #pragma unroll
        for (int nf=0; nf<4; ++nf) bb[nf] = ld_frag(cbase, Cn, n0, nf, koff, lane);
      } else {
        const unsigned short (*xt)[72] = (hop == 1) ? x1t : x2t;
        #pragma unroll
        for (int nf=0; nf<4; ++nf){
          int vl = nf*16 + (lane&15);
          int c0 = koff + ((lane>>4)<<3);
          bb[nf] = *(const bh8*)&xt[vl][c0];
        }
      }
      #pragma unroll
      for (int mf=0; mf<4; ++mf)
        #pragma unroll
        for (int nf=0; nf<4; ++nf)
          g[mf][nf] = __builtin_amdgcn_mfma_f32_16x16x32_bf16(a[mf], bb[nf], g[mf][nf], 0,0,0);
    }
    // epilogue for this chunk of 64 o' rows (16 channels)
    #pragma unroll
    for (int mf = 0; mf < 4; ++mf){
      int oprow = mc*64 + mf*16 + ((lane>>4)<<2);
      int c = oprow >> 2;
      float bi  = bperm[oprow+0];
      float bff = bperm[oprow+1];
      float bgg = bperm[oprow+2];
      float boo = bperm[oprow+3];
      #pragma unroll
      for (int nf = 0; nf < 4; ++nf){
        int vl = nf*16 + (lane & 15);
        int v = n0 + vl;
        float gi = sigm(g[mf][nf][0] + bi);
        float gf = sigm(g[mf][nf][1] + bff);
        float gg =      g[mf][nf][2] + bgg;      // cell gate used raw per reference
        float go = sigm(g[mf][nf][3] + boo);
        size_t ci = ((size_t)b*Cn + c)*Vn + v;
        float cy = gf * cst[ci] + gi * gg;
        cst[ci] = cy;
        float hy = go * tanhfast(cy);
        unsigned short hq = f2bf(hy);
        hyt[vl][c] = hq;
        if (t < 23){
          float cmb = hy + bf2f(xnp[(size_t)v*Cn + c]);
          unsigned short cq = f2bf(cmb);
          cmt[vl][c] = cq;
          comb_mk_nxt[((size_t)b*Cn + c)*Vn + v] = cq;
        }
      }
    }
  }
  __syncthreads();

  // ---- Phase D: coalesced 16B stores of h (and next combc) from LDS
  unsigned short* ysp = ys + ((size_t)(t+1)*Bn + b) * Vn * Cn;
  unsigned short* ccn = combc_nxt + (size_t)b * Vn * Cn;
  #pragma unroll
  for (int e = lane; e < 512; e += 64){
    int vl = e >> 3, c0 = (e & 7) << 3;
    size_t go = (size_t)(n0 + vl) * Cn + c0;
    *(bh8*)(ysp + go) = *(const bh8*)&hyt[vl][c0];
    if (t < 23)
      *(bh8*)(ccn + go) = *(const bh8*)&cmt[vl][c0];
  }
}

// ---------------------------------------------------------------------------
// Output projection via MFMA: out[b][o][v][t] = sum_c Woutb[o][c]*h[t][b][v][c] + bout[o]
// M = o (64), N = (v,t) flattened t-minor (96 per block), K = c (64).
__global__ __launch_bounds__(64) void k_proj(const unsigned short* __restrict__ ys,
    const unsigned short* __restrict__ Woutb, const float* __restrict__ bout,
    float* __restrict__ out){
  int lane = threadIdx.x;
  int b = blockIdx.y;
  int n0 = blockIdx.x * 96;
  f32x4 acc[4][6];
  #pragma unroll
  for (int i=0;i<4;i++)
    #pragma unroll
    for (int j=0;j<6;j++) acc[i][j] = fzero();
  #pragma unroll
  for (int k0 = 0; k0 < 64; k0 += 32){
    bh8 a[4];
    #pragma unroll
    for (int mf=0; mf<4; ++mf) a[mf] = ld_frag(Woutb, 64, 0, mf, k0, lane);
    #pragma unroll
    for (int nf=0; nf<6; ++nf){
      int n = n0 + nf*16 + (lane & 15);
      int v = n / 24, tt = n - v*24;
      bh8 bb = *(const bh8*)(ys + ((size_t)(tt+1)*Bn + b)*Vn*Cn + (size_t)v*Cn
                                 + k0 + ((lane>>4)<<3));
      #pragma unroll
      for (int mf=0; mf<4; ++mf)
        acc[mf][nf] = __builtin_amdgcn_mfma_f32_16x16x32_bf16(a[mf], bb, acc[mf][nf], 0,0,0);
    }
  }
  float* ob = out + (size_t)b * 64 * Vn * Tn;
  #pragma unroll
  for (int mf=0; mf<4; ++mf){
    int o0 = mf*16 + ((lane>>4)<<2);
    float4 bo4 = *(const float4*)(bout + o0);
    #pragma unroll
    for (int nf=0; nf<6; ++nf){
      int n = n0 + nf*16 + (lane & 15);
      int v = n / 24, tt = n - v*24;
      float* op = ob + (size_t)v * Tn + tt;
      op[(size_t)(o0+0)*Vn*Tn] = acc[mf][nf][0] + bo4.x;
      op[(size_t)(o0+1)*Vn*Tn] = acc[mf][nf][1] + bo4.y;
      op[(size_t)(o0+2)*Vn*Tn] = acc[mf][nf][2] + bo4.z;
      op[(size_t)(o0+3)*Vn*Tn] = acc[mf][nf][3] + bo4.w;
    }
  }
}

// ---------------------------------------------------------------------------
extern "C" void kernel_launch(void* const* d_in, const int* in_sizes, int n_in,
                              void* d_out, int out_size, void* d_ws, size_t ws_size,
                              hipStream_t stream){
  const float* x   = (const float*)d_in[0];
  const float* A   = (const float*)d_in[1];
  const float* Wg  = (const float*)d_in[2];
  const float* bg  = (const float*)d_in[3];
  const float* Wo  = (const float*)d_in[4];
  const float* bo  = (const float*)d_in[5];
  float* out = (float*)d_out;

  char* ws = (char*)d_ws;
  size_t off = 0;
  auto alloc = [&](size_t bytes)->char*{
    char* p = ws + off; off = (off + bytes + 255) & ~(size_t)255; return p;
  };
  unsigned short* Abf    = (unsigned short*)alloc((size_t)Vn*Vn*2);
  unsigned short* ATbf   = (unsigned short*)alloc((size_t)Vn*Vn*2);
  unsigned short* A2T    = (unsigned short*)alloc((size_t)Vn*Vn*2);
  float*          A2f    = (float*)         alloc((size_t)Vn*Vn*4);
  unsigned short* Wperm  = (unsigned short*)alloc((size_t)O4*Gn*2);
  float*          bperm  = (float*)         alloc((size_t)O4*4);
  unsigned short* Woutb  = (unsigned short*)alloc((size_t)Cn*Cn*2);
  unsigned short* xTc    = (unsigned short*)alloc((size_t)Tn*Bn*Vn*Cn*2);
  unsigned short* ys     = (unsigned short*)alloc((size_t)(Tn+1)*Bn*Vn*Cn*2);
  unsigned short* combc0 = (unsigned short*)alloc((size_t)Bn*Vn*Cn*2);
  unsigned short* combc1 = (unsigned short*)alloc((size_t)Bn*Vn*Cn*2);
  unsigned short* combm0 = (unsigned short*)alloc((size_t)Bn*Cn*Vn*2);
  unsigned short* combm1 = (unsigned short*)alloc((size_t)Bn*Cn*Vn*2);
  float*          cst    = (float*)         alloc((size_t)Bn*Cn*Vn*4);
  (void)in_sizes; (void)n_in; (void)out_size; (void)ws_size;

  // zero-init recurrent state (h0 plane of ys, c0)
  hipMemsetAsync(ys,  0, (size_t)Bn*Vn*Cn*2, stream);
  hipMemsetAsync(cst, 0, (size_t)Bn*Cn*Vn*4, stream);

  k_prep_w<<<1, 256, 0, stream>>>(Wg, bg, Wo, Wperm, bperm, Woutb);
  k_transq<<<dim3(16,16), 256, 0, stream>>>(A, Abf, ATbf);
  k_gemm_a2<<<dim3(16,16), 64, 0, stream>>>(Abf, ATbf, A2f);
  k_transq<<<dim3(16,16), 256, 0, stream>>>(A2f, (unsigned short*)nullptr, A2T);
  k_transpose_x<<<dim3(64,32), 256, 0, stream>>>(x, xTc);
  k_comb<<<dim3(16,Bn), 256, 0, stream>>>(xTc, ys, combc0, combm0, 0);

  for (int t = 0; t < Tn; ++t){
    unsigned short* cc_cur = (t & 1) ? combc1 : combc0;
    unsigned short* cc_nxt = (t & 1) ? combc0 : combc1;
    unsigned short* cm_cur = (t & 1) ? combm1 : combm0;
    unsigned short* cm_nxt = (t & 1) ? combm0 : combm1;
    k_step<<<dim3(16,Bn), 64, 0, stream>>>(cm_cur, cc_cur, ATbf, A2T, Wperm, bperm,
                                           xTc, cst, ys, cm_nxt, cc_nxt, t);
  }
  k_proj<<<dim3(256,Bn), 64, 0, stream>>>(ys, Woutb, bo, out);
}